// Round 1
// 324.582 us; speedup vs baseline: 1.0170x; 1.0170x over previous
//
#include <hip/hip_runtime.h>

#define BATCH 32
#define TIME  512
#define INF   512
#define HIDF  1024

#define MBT  128          // block tile: bt rows
#define NBH  128          // block tile: h cols
#define KCH  16           // k per chunk
#define NCH  (INF / KCH)  // 32 chunks
#define TILEF (MBT * KCH) // 2048 floats = 8 KB per buffer

// async global->LDS DMA, 16 B per lane, dst = wave-uniform base + lane*16
#define GLD16(g, l) __builtin_amdgcn_global_load_lds(                      \
    (const __attribute__((address_space(1))) void*)(g),                    \
    (__attribute__((address_space(3))) void*)(l), 16, 0, 0)

// ---------------------------------------------------------------------------
// Phase 1: hidden[bt][h] = (sum_k x[bt,k]*W[h,k]) + bias[h], bit-exact vs the
// XLA canonical order: ONE fp32 accumulator per output, fused FMA, k strictly
// ascending, ONE fp32 rounding for +bias.
//
// R8: VGPR=84 under a 170 cap showed the compiler was serializing
// ds_read->FMA in small batches (VALUBusy 62%, 38% idle). Now: explicit
// depth-1 software pipeline over the 4 k-groups (two fragment sets, load
// g+1 while FMA-ing g) + __launch_bounds__(256,2) to give the scheduler
// ~256 VGPRs. FMA order per accumulator unchanged -> bit-exact preserved.
// ---------------------------------------------------------------------------

__device__ __forceinline__ void ldg_frag(const float* __restrict__ xb,
                                         const float* __restrict__ wb,
                                         int wbt, int wh, int lx, int ly, int g,
                                         float4* __restrict__ xf,
                                         float4* __restrict__ wf) {
    const int gx_ = (g ^ (ly & 3)) * 4;   // quad position for x rows
    const int gw_ = (g ^ (lx & 3)) * 4;   // quad position for W rows
    #pragma unroll
    for (int r = 0; r < 8; ++r)
        xf[r] = *(const float4*)(xb + (wbt + ly * 8 + r) * KCH + gx_);
    #pragma unroll
    for (int c = 0; c < 8; ++c)
        wf[c] = *(const float4*)(wb + (wh + lx * 8 + c) * KCH + gw_);
}

__device__ __forceinline__ void fma_frag(float acc[8][8],
                                         const float4* __restrict__ xf,
                                         const float4* __restrict__ wf) {
    // k strictly ascending within the group for every (r,c) chain
    #pragma unroll
    for (int r = 0; r < 8; ++r)
        #pragma unroll
        for (int c = 0; c < 8; ++c)
            acc[r][c] = __fmaf_rn(xf[r].x, wf[c].x, acc[r][c]);
    #pragma unroll
    for (int r = 0; r < 8; ++r)
        #pragma unroll
        for (int c = 0; c < 8; ++c)
            acc[r][c] = __fmaf_rn(xf[r].y, wf[c].y, acc[r][c]);
    #pragma unroll
    for (int r = 0; r < 8; ++r)
        #pragma unroll
        for (int c = 0; c < 8; ++c)
            acc[r][c] = __fmaf_rn(xf[r].z, wf[c].z, acc[r][c]);
    #pragma unroll
    for (int r = 0; r < 8; ++r)
        #pragma unroll
        for (int c = 0; c < 8; ++c)
            acc[r][c] = __fmaf_rn(xf[r].w, wf[c].w, acc[r][c]);
}

__global__ __launch_bounds__(256, 2)
void snn_gemm_seqfma(const float* __restrict__ x, const float* __restrict__ W,
                     const float* __restrict__ bias, float* __restrict__ hidden) {
    __shared__ __align__(16) float xs[2 * TILEF];   // 16 KB
    __shared__ __align__(16) float ws[2 * TILEF];   // 16 KB

    const int tid = threadIdx.x;
    const int l   = tid & 63;
    const int wv  = __builtin_amdgcn_readfirstlane(tid >> 6);  // wave 0..3
    const int lx  = l & 7;           // h octet within wave sub-tile
    const int ly  = (l >> 3) & 7;    // bt octet within wave sub-tile
    const int bt0 = blockIdx.y * MBT;
    const int h0  = blockIdx.x * NBH;
    // wave sub-tile origin inside the 128x128 block tile
    const int wbt = 64 * (wv >> 1);  // bt offset: 0 or 64
    const int wh  = 64 * (wv & 1);   // h  offset: 0 or 64

    // ---- DMA staging: wave wv stages rows 32wv..32wv+31 of x and W ----
    const int rl   = l >> 2;
    const int qs   = l & 3;
    const int rowA = 32 * wv + rl;
    const int rowB = rowA + 16;
    const int qA   = qs ^ ((rowA >> 3) & 3);
    const int qB   = qs ^ ((rowB >> 3) & 3);
    const float* xgA = x + (size_t)(bt0 + rowA) * INF + qA * 4;
    const float* xgB = x + (size_t)(bt0 + rowB) * INF + qB * 4;
    const float* wgA = W + (size_t)(h0 + rowA) * INF + qA * 4;
    const float* wgB = W + (size_t)(h0 + rowB) * INF + qB * 4;
    const int dOffA = (32 * wv) * KCH;        // wave-uniform LDS float offset
    const int dOffB = dOffA + 16 * KCH;

    // ---- prologue: stage chunk 0 into buffer 0 ----
    GLD16(xgA, xs + dOffA);
    GLD16(xgB, xs + dOffB);
    GLD16(wgA, ws + dOffA);
    GLD16(wgB, ws + dOffB);

    float acc[8][8];
    #pragma unroll
    for (int r = 0; r < 8; ++r)
        #pragma unroll
        for (int c = 0; c < 8; ++c) acc[r][c] = 0.0f;

    __syncthreads();   // drains vmcnt -> chunk 0 resident

    for (int kc = 0; kc < NCH; ++kc) {
        const int p  = kc & 1;
        const int np = p ^ 1;

        // ---- issue next chunk's DMAs into the other buffer (async) ----
        if (kc + 1 < NCH) {
            const int so = (kc + 1) * KCH;    // float offset within a row
            float* xd = xs + np * TILEF;
            float* wd = ws + np * TILEF;
            GLD16(xgA + so, xd + dOffA);
            GLD16(xgB + so, xd + dOffB);
            GLD16(wgA + so, wd + dOffA);
            GLD16(wgB + so, wd + dOffB);
        }

        // ---- compute on current buffer: 4 groups of 4 k, g ascending ----
        // Depth-1 software pipeline: fragments for group g+1 are loaded
        // while group g's FMAs run. Two explicit fragment sets force the
        // decoupling the 84-VGPR schedule couldn't do.
        const float* xb = xs + p * TILEF;
        const float* wb = ws + p * TILEF;
        float4 xa[8], wa[8], xc[8], wc[8];
        ldg_frag(xb, wb, wbt, wh, lx, ly, 0, xa, wa);
        ldg_frag(xb, wb, wbt, wh, lx, ly, 1, xc, wc);
        fma_frag(acc, xa, wa);                               // g=0
        ldg_frag(xb, wb, wbt, wh, lx, ly, 2, xa, wa);
        fma_frag(acc, xc, wc);                               // g=1
        ldg_frag(xb, wb, wbt, wh, lx, ly, 3, xc, wc);
        fma_frag(acc, xa, wa);                               // g=2
        fma_frag(acc, xc, wc);                               // g=3

        __syncthreads();   // all waves done with buf p; buf np's DMAs drained
    }

    // ---- epilogue: one fp32 rounding for bias, float4 stores ----
    float bv[8];
    #pragma unroll
    for (int c = 0; c < 8; ++c) bv[c] = bias[h0 + wh + lx * 8 + c];
    #pragma unroll
    for (int r = 0; r < 8; ++r) {
        float* orow = hidden + (size_t)(bt0 + wbt + ly * 8 + r) * HIDF
                             + h0 + wh + lx * 8;
        float4 o0, o1;
        o0.x = __fadd_rn(acc[r][0], bv[0]);
        o0.y = __fadd_rn(acc[r][1], bv[1]);
        o0.z = __fadd_rn(acc[r][2], bv[2]);
        o0.w = __fadd_rn(acc[r][3], bv[3]);
        o1.x = __fadd_rn(acc[r][4], bv[4]);
        o1.y = __fadd_rn(acc[r][5], bv[5]);
        o1.z = __fadd_rn(acc[r][6], bv[6]);
        o1.w = __fadd_rn(acc[r][7], bv[7]);
        ((float4*)orow)[0] = o0;
        ((float4*)orow)[1] = o1;
    }
}

// ---------------------------------------------------------------------------
// Phase 2: in-place LIF scan over t per (b,h) column, fp32:
//   mem = fl32(0.5*mem + h_t); spk = mem > 1.0f; hard reset to 0.
// R8: old grid was 128 blocks x 256 -> only half the CUs had work. Now
// 512 blocks x 64 (2 waves on every CU) + explicit A/B double-buffered
// 32-deep segments so the next segment's loads are in flight while the
// current segment's sequential mem-chain runs. Math order unchanged.
// ---------------------------------------------------------------------------
#define SEG 32

__global__ __launch_bounds__(64)
void snn_scan_np(float* __restrict__ io) {
    const int n = blockIdx.x * 64 + threadIdx.x;   // 0..32767
    const int b = n >> 10;
    const int h = n & 1023;
    float* p = io + (size_t)b * TIME * HIDF + h;

    float A[SEG], B[SEG];
    float mem = 0.0f;

    #pragma unroll
    for (int u = 0; u < SEG; ++u) A[u] = p[u * HIDF];

    for (int tb = 0; tb < TIME / SEG; tb += 2) {
        // prefetch segment tb+1 into B (loads fly under A's mem-chain)
        #pragma unroll
        for (int u = 0; u < SEG; ++u) B[u] = p[((tb + 1) * SEG + u) * HIDF];
        // process + store segment tb from A
        #pragma unroll
        for (int u = 0; u < SEG; ++u) {
            mem = __fadd_rn(__fmul_rn(0.5f, mem), A[u]);
            const bool s = mem > 1.0f;
            p[(tb * SEG + u) * HIDF] = s ? 1.0f : 0.0f;
            if (s) mem = 0.0f;
        }
        // prefetch segment tb+2 into A
        if (tb + 2 < TIME / SEG) {
            #pragma unroll
            for (int u = 0; u < SEG; ++u) A[u] = p[((tb + 2) * SEG + u) * HIDF];
        }
        // process + store segment tb+1 from B
        #pragma unroll
        for (int u = 0; u < SEG; ++u) {
            mem = __fadd_rn(__fmul_rn(0.5f, mem), B[u]);
            const bool s = mem > 1.0f;
            p[((tb + 1) * SEG + u) * HIDF] = s ? 1.0f : 0.0f;
            if (s) mem = 0.0f;
        }
    }
}

extern "C" void kernel_launch(void* const* d_in, const int* in_sizes, int n_in,
                              void* d_out, int out_size, void* d_ws, size_t ws_size,
                              hipStream_t stream) {
    const float* x    = (const float*)d_in[0];   // [32, 512, 512]
    const float* W    = (const float*)d_in[1];   // [1024, 512]
    const float* bias = (const float*)d_in[2];   // [1024]
    float* out = (float*)d_out;                  // [32, 512, 1024]

    dim3 g1(HIDF / NBH, (BATCH * TIME) / MBT);   // (8, 128) = 1024 blocks
    snn_gemm_seqfma<<<g1, 256, 0, stream>>>(x, W, bias, out);

    snn_scan_np<<<(BATCH * HIDF) / 64, 64, 0, stream>>>(out);
}